// Round 5
// baseline (77746.130 us; speedup 1.0000x reference)
//
#include <hip/hip_runtime.h>
#include <math.h>
#include <stdint.h>

#define Bn 256
#define Tn 256
#define Dn 512
#define UNITSn 1024
#define NCn 512
#define G4n 4096
#define KTn 1536   // 512 (x) + 1024 (h)
#define NT 48      // K tiles of 32

typedef unsigned long long u64;

__device__ __forceinline__ double hsigd(double z) {
    return fmin(fmax(0.2 * z + 0.5, 0.0), 1.0);
}

// pack logit+col into u64: fixed-point (logit+2048)*2^40 (<<10) | (1023-col)
// monotone in logit (9.1e-13 resolution), ties -> smallest col (numpy first-max)
__device__ __forceinline__ u64 packlc(double v, int col) {
    double s = (v + 2048.0) * 1099511627776.0;   // 2^40
    u64 q = (u64)s;                              // < 2^53
    return (q << 10) | (u64)(1023 - col);
}

// ---------------- weight pre-conversion: Wd[k][4096] = fp64 of [Wx; U] ----------------
__global__ void convert_weights(const float* __restrict__ W, const float* __restrict__ U,
                                double* __restrict__ Wd)
{
    size_t stride = (size_t)gridDim.x * blockDim.x;
    for (size_t i = (size_t)blockIdx.x * blockDim.x + threadIdx.x;
         i < (size_t)KTn * G4n; i += stride) {
        int k = (int)(i >> 12);
        int j = (int)(i & 4095);
        float v = (k < Dn) ? W[i] : U[(size_t)(k - Dn) * G4n + j];
        Wd[i] = (double)v;
    }
}

// ---------------- Kernel A (scalar-B path): z = [x|h]@[Wx;U] -> gates -> c,h ----------
// Block: 64 batch rows x 32 cols (4 gates x 8 units). 4 waves; wave w = gate w,
// lane = row. A staged in LDS [row][k] fp64 (1 ds_read_b128 per 2 k); B fetched
// via s_load from fp64 Wd with a wave-uniform pointer -> v_fma_f64 scalar operand.
#define SG_STR 34            // doubles per As row (68 dwords = 4 mod 32: conflict-free)
#define SG_TILE (64 * SG_STR)

__global__ __launch_bounds__(256, 2) void lstm_step_sg(
    const float* __restrict__ x, const double* __restrict__ Wd,
    const float* __restrict__ W, const float* __restrict__ bias,
    const double* __restrict__ hin, double* __restrict__ hout,
    double* __restrict__ cst,
    const u64* __restrict__ slots_prev, u64* __restrict__ slots_cur,
    int* __restrict__ out, int t)
{
    __shared__ __align__(16) double smem[2 * SG_TILE];   // 34816 B; zex aliases later

    const int tid = threadIdx.x;
    const int bid = blockIdx.x;
    const int ct = bid & 127;          // col tile: 8 units
    const int yt = bid >> 7;           // row tile: 64 rows
    const int u0 = ct * 8;
    const int rowbase = yt * 64;

    if (ct == 0 && tid < 64) slots_cur[rowbase + tid] = 0ull;

    // ---- staging map: row = tid>>2 (0..63), k0 = (tid&3)*8 ----
    const int sr = tid >> 2;
    const int sk0 = (tid & 3) * 8;
    const float* xrow = x + (size_t)(rowbase + sr) * (Tn * Dn) + (size_t)t * Dn;
    const double* hrow = hin + (size_t)(rowbase + sr) * UNITSn;

    double apf[8];
    auto prefetch = [&](int it) {
        int k0 = it * 32 + sk0;
        if (k0 < Dn) {
            float4 v0 = *(const float4*)(xrow + k0);
            float4 v1 = *(const float4*)(xrow + k0 + 4);
            apf[0] = (double)v0.x; apf[1] = (double)v0.y;
            apf[2] = (double)v0.z; apf[3] = (double)v0.w;
            apf[4] = (double)v1.x; apf[5] = (double)v1.y;
            apf[6] = (double)v1.z; apf[7] = (double)v1.w;
        } else {
            const double* hp = hrow + (k0 - Dn);
            double2 a = *(const double2*)(hp + 0);
            double2 b = *(const double2*)(hp + 2);
            double2 c2 = *(const double2*)(hp + 4);
            double2 d = *(const double2*)(hp + 6);
            apf[0] = a.x; apf[1] = a.y; apf[2] = b.x; apf[3] = b.y;
            apf[4] = c2.x; apf[5] = c2.y; apf[6] = d.x; apf[7] = d.y;
        }
    };
    auto store_tiles = [&](int p) {
        double* As = smem + p * SG_TILE;
        #pragma unroll
        for (int j = 0; j < 8; j += 2) {
            double2 w2; w2.x = apf[j]; w2.y = apf[j + 1];
            *(double2*)&As[sr * SG_STR + sk0 + j] = w2;
        }
    };

    // ---- wave-uniform B pointer (forces SMEM path) ----
    const int wv = __builtin_amdgcn_readfirstlane(tid >> 6);   // gate 0..3
    const double* Bbase = Wd + (size_t)wv * UNITSn + u0;

    const int lane = tid & 63;   // = batch row within tile
    double acc[8];
    #pragma unroll
    for (int j = 0; j < 8; j++) acc[j] = 0.0;

    prefetch(0);
    store_tiles(0);
    __syncthreads();

    int p = 0;
    for (int it = 0; it < NT; it++) {
        if (it + 1 < NT) prefetch(it + 1);
        {
            const double* As = smem + p * SG_TILE;
            const double* Bt = Bbase + (size_t)it * 32 * G4n;
            #pragma unroll
            for (int kk = 0; kk < 32; kk += 2) {
                double2 a2 = *(const double2*)&As[lane * SG_STR + kk];
                #pragma unroll
                for (int j = 0; j < 8; j++)
                    acc[j] = fma(a2.x, Bt[(size_t)kk * G4n + j], acc[j]);
                #pragma unroll
                for (int j = 0; j < 8; j++)
                    acc[j] = fma(a2.y, Bt[(size_t)(kk + 1) * G4n + j], acc[j]);
            }
        }
        if (it + 1 < NT) store_tiles(p ^ 1);
        __syncthreads();
        p ^= 1;
    }

    // ---- gate exchange: zex[4][64][9] aliases smem (post-barrier) ----
    double* zex = smem;
    #pragma unroll
    for (int j = 0; j < 8; j++)
        zex[(wv * 64 + lane) * 9 + j] = acc[j];
    __syncthreads();

    // ---- epilogue: 2 cells/thread: row = tid&63, units euu and euu+4 ----
    const int er = tid & 63;
    const int euu = tid >> 6;
    const int row = rowbase + er;
    int idx = 0;
    if (t > 0) {
        u64 sp = slots_prev[row];
        idx = 1023 - (int)(sp & 1023ull);
        if (ct == 0 && euu == 0) out[(size_t)row * Tn + (t - 1)] = idx;
    }
    const float* wrow = W + (size_t)(Dn + idx) * G4n;

    #pragma unroll
    for (int s = 0; s < 2; s++) {
        int uu = euu + s * 4;
        int ug = u0 + uu;
        double zi = zex[(0 * 64 + er) * 9 + uu] + (double)bias[ug];
        double zf = zex[(1 * 64 + er) * 9 + uu] + (double)bias[UNITSn + ug];
        double zc = zex[(2 * 64 + er) * 9 + uu] + (double)bias[2 * UNITSn + ug];
        double zo = zex[(3 * 64 + er) * 9 + uu] + (double)bias[3 * UNITSn + ug];
        if (t > 0) {
            zi += (double)wrow[ug];
            zf += (double)wrow[UNITSn + ug];
            zc += (double)wrow[2 * UNITSn + ug];
            zo += (double)wrow[3 * UNITSn + ug];
        }
        size_t off = (size_t)row * UNITSn + ug;
        double cold = cst[off];
        double ig = hsigd(zi), fg = hsigd(zf), og = hsigd(zo);
        double cn = fg * cold + ig * tanh(zc);
        double hn = og * tanh(cn);
        cst[off] = cn;
        hout[off] = hn;
    }
}

// ---------------- Kernel A (fallback, round-4 proven): used when ws is small --------
__global__ __launch_bounds__(256, 2) void lstm_step(
    const float* __restrict__ x, const float* __restrict__ W,
    const float* __restrict__ U, const float* __restrict__ bias,
    const double* __restrict__ hin, double* __restrict__ hout,
    double* __restrict__ cst,
    const u64* __restrict__ slots_prev, u64* __restrict__ slots_cur,
    int* __restrict__ out, int t)
{
    __shared__ __align__(16) double smem[6144];

    const int tid = threadIdx.x;
    const int bid = blockIdx.x;
    const int ut = bid & 127;
    const int yt = bid >> 7;
    const int u0 = ut * 8;
    const int rowbase = yt * 64;

    if (ut == 0 && tid < 64) slots_cur[rowbase + tid] = 0ull;

    const int la_row = tid >> 2;
    const int la_k0 = (tid & 3) * 8;
    const int lb_k  = tid >> 3;
    const int lb_c4 = (tid & 7) * 4;
    const int lb_gate = lb_c4 >> 3;
    const int lb_uoff = lb_c4 & 7;

    const float* xrow = x + (size_t)(rowbase + la_row) * (Tn * Dn) + (size_t)t * Dn;
    const double* hrow = hin + (size_t)(rowbase + la_row) * UNITSn;

    double a_pf[8];
    double b_pf[4];

    auto prefetch = [&](int it) {
        int kg = it * 32;
        int k0 = kg + la_k0;
        if (k0 < Dn) {
            float4 v0 = *(const float4*)(xrow + k0);
            float4 v1 = *(const float4*)(xrow + k0 + 4);
            a_pf[0] = (double)v0.x; a_pf[1] = (double)v0.y;
            a_pf[2] = (double)v0.z; a_pf[3] = (double)v0.w;
            a_pf[4] = (double)v1.x; a_pf[5] = (double)v1.y;
            a_pf[6] = (double)v1.z; a_pf[7] = (double)v1.w;
        } else {
            const double* hp = hrow + (k0 - Dn);
            double2 h0v = *(const double2*)(hp + 0);
            double2 h1v = *(const double2*)(hp + 2);
            double2 h2v = *(const double2*)(hp + 4);
            double2 h3v = *(const double2*)(hp + 6);
            a_pf[0] = h0v.x; a_pf[1] = h0v.y; a_pf[2] = h1v.x; a_pf[3] = h1v.y;
            a_pf[4] = h2v.x; a_pf[5] = h2v.y; a_pf[6] = h3v.x; a_pf[7] = h3v.y;
        }
        int kB = kg + lb_k;
        const float* rowp = (kB < Dn) ? (W + (size_t)kB * G4n)
                                      : (U + (size_t)(kB - Dn) * G4n);
        float4 wv = *(const float4*)(rowp + lb_gate * UNITSn + u0 + lb_uoff);
        b_pf[0] = (double)wv.x; b_pf[1] = (double)wv.y;
        b_pf[2] = (double)wv.z; b_pf[3] = (double)wv.w;
    };
    auto store_tiles = [&](int p) {
        double* As = smem + p * 2048;
        double* Bs = smem + 4096 + p * 1024;
        #pragma unroll
        for (int j = 0; j < 8; j++) As[(la_k0 + j) * 64 + la_row] = a_pf[j];
        double2 w0; w0.x = b_pf[0]; w0.y = b_pf[1];
        double2 w1; w1.x = b_pf[2]; w1.y = b_pf[3];
        *(double2*)&Bs[lb_k * 32 + lb_c4] = w0;
        *(double2*)&Bs[lb_k * 32 + lb_c4 + 2] = w1;
    };

    const int lane = tid & 63;
    const int wv_ = tid >> 6;
    const int ri = lane >> 3;
    const int cj = lane & 7;
    const int rb = wv_ * 16 + ri * 2;

    double acc[2][4];
    #pragma unroll
    for (int i = 0; i < 2; i++)
        #pragma unroll
        for (int j = 0; j < 4; j++) acc[i][j] = 0.0;

    prefetch(0);
    store_tiles(0);
    __syncthreads();

    int p = 0;
    for (int it = 0; it < NT; it++) {
        if (it + 1 < NT) prefetch(it + 1);
        {
            const double* As = smem + p * 2048;
            const double* Bs = smem + 4096 + p * 1024;
            #pragma unroll
            for (int k = 0; k < 32; k++) {
                double2 a2 = *(const double2*)&As[k * 64 + rb];
                double2 b0 = *(const double2*)&Bs[k * 32 + cj * 4];
                double2 b1 = *(const double2*)&Bs[k * 32 + cj * 4 + 2];
                acc[0][0] = fma(a2.x, b0.x, acc[0][0]);
                acc[0][1] = fma(a2.x, b0.y, acc[0][1]);
                acc[0][2] = fma(a2.x, b1.x, acc[0][2]);
                acc[0][3] = fma(a2.x, b1.y, acc[0][3]);
                acc[1][0] = fma(a2.y, b0.x, acc[1][0]);
                acc[1][1] = fma(a2.y, b0.y, acc[1][1]);
                acc[1][2] = fma(a2.y, b1.x, acc[1][2]);
                acc[1][3] = fma(a2.y, b1.y, acc[1][3]);
            }
        }
        if (it + 1 < NT) store_tiles(p ^ 1);
        __syncthreads();
        p ^= 1;
    }

    double* zex = smem;
    #pragma unroll
    for (int i = 0; i < 2; i++) {
        double2 z0; z0.x = acc[i][0]; z0.y = acc[i][1];
        double2 z1; z1.x = acc[i][2]; z1.y = acc[i][3];
        *(double2*)&zex[(rb + i) * 32 + cj * 4] = z0;
        *(double2*)&zex[(rb + i) * 32 + cj * 4 + 2] = z1;
    }
    __syncthreads();

    const int eu = tid & 7;
    const int rr = tid >> 3;
    const int ug = u0 + eu;
    const double bi0 = (double)bias[ug];
    const double bf0 = (double)bias[UNITSn + ug];
    const double bc0 = (double)bias[2 * UNITSn + ug];
    const double bo0 = (double)bias[3 * UNITSn + ug];

    #pragma unroll
    for (int s = 0; s < 2; s++) {
        int r = rr + 32 * s;
        int row = rowbase + r;
        double zi = zex[r * 32 + eu]      + bi0;
        double zf = zex[r * 32 + 8 + eu]  + bf0;
        double zc = zex[r * 32 + 16 + eu] + bc0;
        double zo = zex[r * 32 + 24 + eu] + bo0;
        if (t > 0) {
            u64 sp = slots_prev[row];
            int idx = 1023 - (int)(sp & 1023ull);
            const float* wrow = W + (size_t)(Dn + idx) * G4n + ug;
            zi += (double)wrow[0];
            zf += (double)wrow[UNITSn];
            zc += (double)wrow[2 * UNITSn];
            zo += (double)wrow[3 * UNITSn];
            if (ut == 0 && eu == 0) out[(size_t)row * Tn + (t - 1)] = idx;
        }
        size_t off = (size_t)row * UNITSn + ug;
        double cold = cst[off];
        double ig = hsigd(zi), fg = hsigd(zf), og = hsigd(zo);
        double cn = fg * cold + ig * tanh(zc);
        double hn = og * tanh(cn);
        cst[off] = cn;
        hout[off] = hn;
    }
}

// ---------------- Kernel C: logits = h@Wout + bout (fp64), fused argmax ----
#define C_RT 8
#define C_CT 64
#define C_KC 32

__global__ __launch_bounds__(256) void logits_argmax(
    const double* __restrict__ h, const float* __restrict__ Wout,
    const float* __restrict__ bout, u64* __restrict__ slots)
{
    __shared__ double Hs[C_KC][9];
    __shared__ float  Ws[C_KC][C_CT];

    const int tid = threadIdx.x;
    const int ty = tid >> 5;
    const int tx = tid & 31;
    const int rbase = blockIdx.y * C_RT;
    const int cbase = blockIdx.x * C_CT;

    double acc0 = 0.0, acc1 = 0.0;

    const int lh_row = tid >> 5;
    const int lh_kk = tid & 31;
    const int lw_kk = tid >> 4;
    const int lw_j0 = (tid & 15) * 4;

    for (int kb = 0; kb < UNITSn; kb += C_KC) {
        Hs[lh_kk][lh_row] = h[(size_t)(rbase + lh_row) * UNITSn + kb + lh_kk];
        #pragma unroll
        for (int it = 0; it < 2; it++) {
            int kk = lw_kk + it * 16;
            float4 v = *(const float4*)(Wout + (size_t)(kb + kk) * NCn + cbase + lw_j0);
            *(float4*)&Ws[kk][lw_j0] = v;
        }
        __syncthreads();
        #pragma unroll
        for (int kk = 0; kk < C_KC; kk++) {
            double a = Hs[kk][ty];
            float2 wv = *(const float2*)&Ws[kk][tx * 2];
            acc0 = fma(a, (double)wv.x, acc0);
            acc1 = fma(a, (double)wv.y, acc1);
        }
        __syncthreads();
    }

    int col0 = cbase + tx * 2;
    double lg0 = acc0 + (double)bout[col0];
    double lg1 = acc1 + (double)bout[col0 + 1];

    u64 p0 = packlc(lg0, col0);
    u64 p1 = packlc(lg1, col0 + 1);
    u64 best = (p0 > p1) ? p0 : p1;
    #pragma unroll
    for (int off = 16; off >= 1; off >>= 1) {
        u64 o = __shfl_down(best, off, 32);
        if (o > best) best = o;
    }
    if (tx == 0) atomicMax(&slots[rbase + ty], best);
}

// ---------------- final step decode ----------------
__global__ void final_decode(const u64* __restrict__ slots, int* __restrict__ out) {
    int b = threadIdx.x;
    u64 s = slots[b];
    out[(size_t)b * Tn + (Tn - 1)] = 1023 - (int)(s & 1023ull);
}

extern "C" void kernel_launch(void* const* d_in, const int* in_sizes, int n_in,
                              void* d_out, int out_size, void* d_ws, size_t ws_size,
                              hipStream_t stream) {
    const float* x    = (const float*)d_in[0];
    const float* W    = (const float*)d_in[1];
    const float* U    = (const float*)d_in[2];
    const float* bias = (const float*)d_in[3];
    const float* Wout = (const float*)d_in[4];
    const float* bout = (const float*)d_in[5];
    int* out = (int*)d_out;
    char* ws = (char*)d_ws;

    // ws layout: h0 (2MB) | h1 (2MB) | c (2MB) | slots0/1 (4KB) | [big path: Wd 48MB @8MB]
    double* h0 = (double*)(ws);
    double* h1 = (double*)(ws + (2u << 20));
    double* c  = (double*)(ws + (4u << 20));
    u64* slots0 = (u64*)(ws + (6u << 20));
    u64* slots1 = (u64*)(ws + (6u << 20) + 2048);
    double* Wd  = (double*)(ws + (8u << 20));

    const size_t NEED = (8ull << 20) + (size_t)KTn * G4n * 8;   // 56 MB+8MB
    const bool big = ws_size >= NEED;

    hipMemsetAsync(d_ws, 0, (6u << 20) + 4096, stream);
    if (big) convert_weights<<<1024, 256, 0, stream>>>(W, U, Wd);

    for (int t = 0; t < Tn; t++) {
        double* hin  = (t & 1) ? h1 : h0;
        double* hout = (t & 1) ? h0 : h1;
        u64* sprev = (t & 1) ? slots0 : slots1;   // written by C(t-1)
        u64* scur  = (t & 1) ? slots1 : slots0;   // zeroed by A(t), written by C(t)
        if (big) {
            lstm_step_sg<<<dim3(512), 256, 0, stream>>>(x, Wd, W, bias, hin, hout, c,
                                                        sprev, scur, out, t);
        } else {
            lstm_step<<<dim3(512), 256, 0, stream>>>(x, W, U, bias, hin, hout, c,
                                                     sprev, scur, out, t);
        }
        logits_argmax<<<dim3(8, 32), 256, 0, stream>>>(hout, Wout, bout, scur);
    }
    // t = T-1 = 255 (odd) -> its slots live in slots1
    final_decode<<<1, Bn, 0, stream>>>(slots1, out);
}

// Round 6
// 31276.724 us; speedup vs baseline: 2.4858x; 2.4858x over previous
//
#include <hip/hip_runtime.h>
#include <math.h>
#include <stdint.h>

#define Bn 256
#define Tn 256
#define Dn 512
#define UNITSn 1024
#define NCn 512
#define G4n 4096
#define KTn 1536   // 512 (x) + 1024 (h)
#define NT 48      // K tiles of 32

typedef unsigned long long u64;
typedef __attribute__((ext_vector_type(4))) double d4;

__device__ __forceinline__ double hsigd(double z) {
    return fmin(fmax(0.2 * z + 0.5, 0.0), 1.0);
}

// pack logit+col into u64: fixed-point (logit+2048)*2^40 (<<10) | (1023-col)
__device__ __forceinline__ u64 packlc(double v, int col) {
    double s = (v + 2048.0) * 1099511627776.0;   // 2^40
    u64 q = (u64)s;                              // < 2^53
    return (q << 10) | (u64)(1023 - col);
}

// ---------------- weight pre-conversion: Wd[k][4096] = fp64 of [Wx; U] ----------------
__global__ void convert_weights(const float* __restrict__ W, const float* __restrict__ U,
                                double* __restrict__ Wd)
{
    size_t stride = (size_t)gridDim.x * blockDim.x;
    for (size_t i = (size_t)blockIdx.x * blockDim.x + threadIdx.x;
         i < (size_t)KTn * G4n; i += stride) {
        int k = (int)(i >> 12);
        int j = (int)(i & 4095);
        float v = (k < Dn) ? W[i] : U[(size_t)(k - Dn) * G4n + j];
        Wd[i] = (double)v;
    }
}

// ---------------- Kernel A (MFMA f64): z = [x|h]@[Wx;U] -> gates -> c,h ----------
// Tile: 64 batch rows x 32 cols (4 gates x 8 units). Grid 512 -> 2 blocks/CU.
// 256 thr = 4 waves; wave w = rows [16w,16w+16) x 2 col-tiles of 16x16.
// C/D register layout SELF-CALIBRATED via probe MFMAs (immune to layout errata).
#define AS_STR 34   // doubles per A row (k 0..31 + pad2)
#define BS_STR 34   // doubles per B k-row (32 cols + pad2)
#define AS_TILE (64 * AS_STR)    // 2176
#define BS_TILE (32 * BS_STR)    // 1088

__global__ __launch_bounds__(256, 2) void lstm_step_mfma(
    const float* __restrict__ x, const double* __restrict__ Wd,
    const float* __restrict__ W, const float* __restrict__ bias,
    const double* __restrict__ hin, double* __restrict__ hout,
    double* __restrict__ cst,
    const u64* __restrict__ slots_prev, u64* __restrict__ slots_cur,
    int* __restrict__ out, int t)
{
    // As0=0, As1=2176, Bs0=4352, Bs1=5440; total 6528 doubles = 52224 B.
    // zex[64][33] = 2112 doubles aliases As0 after the final barrier (legal: flat array).
    __shared__ __align__(16) double smem[2 * AS_TILE + 2 * BS_TILE];

    const int tid = threadIdx.x;
    const int bid = blockIdx.x;
    const int ct_ = bid & 127;         // col tile: 8 units
    const int yt = bid >> 7;           // row tile: 64 rows
    const int u0 = ct_ * 8;
    const int rowbase = yt * 64;

    if (ct_ == 0 && tid < 64) slots_cur[rowbase + tid] = 0ull;

    // ---- staging maps ----
    const int sr = tid >> 2;                // A: row 0..63
    const int sk0 = (tid & 3) * 8;          // A: k base 0,8,16,24
    const int lb_k = tid >> 3;              // B: k 0..31
    const int lb_c4 = (tid & 7) * 4;        // B: col base 0,4,...,28
    const int lb_gate = lb_c4 >> 3;
    const int lb_uoff = lb_c4 & 7;          // 0 or 4

    const float* xrow = x + (size_t)(rowbase + sr) * (Tn * Dn) + (size_t)t * Dn;
    const double* hrow = hin + (size_t)(rowbase + sr) * UNITSn;
    const double* wb = Wd + (size_t)lb_gate * UNITSn + u0 + lb_uoff;

    double apf[8];
    double2 bpf[2];

    auto prefetch = [&](int it) {
        int k0 = it * 32 + sk0;
        if (k0 < Dn) {
            float4 v0 = *(const float4*)(xrow + k0);
            float4 v1 = *(const float4*)(xrow + k0 + 4);
            apf[0] = (double)v0.x; apf[1] = (double)v0.y;
            apf[2] = (double)v0.z; apf[3] = (double)v0.w;
            apf[4] = (double)v1.x; apf[5] = (double)v1.y;
            apf[6] = (double)v1.z; apf[7] = (double)v1.w;
        } else {
            const double* hp = hrow + (k0 - Dn);
            double2 a = *(const double2*)(hp + 0);
            double2 b = *(const double2*)(hp + 2);
            double2 c2 = *(const double2*)(hp + 4);
            double2 d = *(const double2*)(hp + 6);
            apf[0] = a.x; apf[1] = a.y; apf[2] = b.x; apf[3] = b.y;
            apf[4] = c2.x; apf[5] = c2.y; apf[6] = d.x; apf[7] = d.y;
        }
        const double* bp = wb + (size_t)(it * 32 + lb_k) * G4n;
        bpf[0] = *(const double2*)(bp);
        bpf[1] = *(const double2*)(bp + 2);
    };
    auto store_tiles = [&](int p) {
        double* As = smem + p * AS_TILE;
        double* Bs = smem + 2 * AS_TILE + p * BS_TILE;
        #pragma unroll
        for (int j = 0; j < 8; j += 2) {
            double2 w2; w2.x = apf[j]; w2.y = apf[j + 1];
            *(double2*)&As[sr * AS_STR + sk0 + j] = w2;
        }
        *(double2*)&Bs[lb_k * BS_STR + lb_c4] = bpf[0];
        *(double2*)&Bs[lb_k * BS_STR + lb_c4 + 2] = bpf[1];
    };

    // ---- MFMA lane mapping (A: m=lane%16,k=lane/16; B: n=lane%16,k=lane/16) ----
    const int lane = tid & 63;
    const int wvi = tid >> 6;
    const int rs = wvi * 16;           // row strip base
    const int ml = lane & 15;          // m / n within tile
    const int kl = lane >> 4;          // k within quad

    // ---- self-calibrate C/D layout: D[m][n]=m probe, D[m][n]=n probe ----
    d4 zero4 = {0.0, 0.0, 0.0, 0.0};
    double onek0 = (kl == 0) ? 1.0 : 0.0;
    double mk0   = (kl == 0) ? (double)ml : 0.0;
    d4 prow = __builtin_amdgcn_mfma_f64_16x16x4f64(mk0, onek0, zero4, 0, 0, 0);
    d4 pcol = __builtin_amdgcn_mfma_f64_16x16x4f64(onek0, mk0, zero4, 0, 0, 0);
    int zoff[4];
    #pragma unroll
    for (int r = 0; r < 4; r++)
        zoff[r] = (rs + (int)prow[r]) * 33 + (int)pcol[r];

    d4 acc[2];
    acc[0] = zero4; acc[1] = zero4;

    prefetch(0);
    store_tiles(0);
    __syncthreads();

    int p = 0;
    for (int it = 0; it < NT; it++) {
        if (it + 1 < NT) prefetch(it + 1);
        {
            const double* As = smem + p * AS_TILE;
            const double* Bs = smem + 2 * AS_TILE + p * BS_TILE;
            #pragma unroll
            for (int kq = 0; kq < 8; kq++) {
                double a = As[(rs + ml) * AS_STR + kq * 4 + kl];
                double b0 = Bs[(kq * 4 + kl) * BS_STR + ml];
                double b1 = Bs[(kq * 4 + kl) * BS_STR + 16 + ml];
                acc[0] = __builtin_amdgcn_mfma_f64_16x16x4f64(a, b0, acc[0], 0, 0, 0);
                acc[1] = __builtin_amdgcn_mfma_f64_16x16x4f64(a, b1, acc[1], 0, 0, 0);
            }
        }
        if (it + 1 < NT) store_tiles(p ^ 1);
        __syncthreads();
        p ^= 1;
    }

    // ---- gate exchange: zex[64][33] aliases As0 (post-final-barrier) ----
    double* zex = smem;
    #pragma unroll
    for (int r = 0; r < 4; r++) {
        zex[zoff[r]] = acc[0][r];
        zex[zoff[r] + 16] = acc[1][r];
    }
    __syncthreads();

    // ---- epilogue: 2 cells/thread (rows rr, rr+32; unit eu) ----
    const int eu = tid & 7;
    const int rr = tid >> 3;           // 0..31
    const int ug = u0 + eu;
    const double bi0 = (double)bias[ug];
    const double bf0 = (double)bias[UNITSn + ug];
    const double bc0 = (double)bias[2 * UNITSn + ug];
    const double bo0 = (double)bias[3 * UNITSn + ug];

    #pragma unroll
    for (int s = 0; s < 2; s++) {
        int r = rr + 32 * s;
        int row = rowbase + r;
        double zi = zex[r * 33 + eu]      + bi0;
        double zf = zex[r * 33 + 8 + eu]  + bf0;
        double zc = zex[r * 33 + 16 + eu] + bc0;
        double zo = zex[r * 33 + 24 + eu] + bo0;
        if (t > 0) {
            u64 sp = slots_prev[row];
            int idx = 1023 - (int)(sp & 1023ull);
            const float* wrow = W + (size_t)(Dn + idx) * G4n + ug;
            zi += (double)wrow[0];
            zf += (double)wrow[UNITSn];
            zc += (double)wrow[2 * UNITSn];
            zo += (double)wrow[3 * UNITSn];
            if (ct_ == 0 && eu == 0) out[(size_t)row * Tn + (t - 1)] = idx;
        }
        size_t off = (size_t)row * UNITSn + ug;
        double cold = cst[off];
        double ig = hsigd(zi), fg = hsigd(zf), og = hsigd(zo);
        double cn = fg * cold + ig * tanh(zc);
        double hn = og * tanh(cn);
        cst[off] = cn;
        hout[off] = hn;
    }
}

// ---------------- Kernel A fallback (round-4 proven, vector fp64) --------
__global__ __launch_bounds__(256, 2) void lstm_step(
    const float* __restrict__ x, const float* __restrict__ W,
    const float* __restrict__ U, const float* __restrict__ bias,
    const double* __restrict__ hin, double* __restrict__ hout,
    double* __restrict__ cst,
    const u64* __restrict__ slots_prev, u64* __restrict__ slots_cur,
    int* __restrict__ out, int t)
{
    __shared__ __align__(16) double smem[6144];

    const int tid = threadIdx.x;
    const int bid = blockIdx.x;
    const int ut = bid & 127;
    const int yt = bid >> 7;
    const int u0 = ut * 8;
    const int rowbase = yt * 64;

    if (ut == 0 && tid < 64) slots_cur[rowbase + tid] = 0ull;

    const int la_row = tid >> 2;
    const int la_k0 = (tid & 3) * 8;
    const int lb_k  = tid >> 3;
    const int lb_c4 = (tid & 7) * 4;
    const int lb_gate = lb_c4 >> 3;
    const int lb_uoff = lb_c4 & 7;

    const float* xrow = x + (size_t)(rowbase + la_row) * (Tn * Dn) + (size_t)t * Dn;
    const double* hrow = hin + (size_t)(rowbase + la_row) * UNITSn;

    double a_pf[8];
    double b_pf[4];

    auto prefetch = [&](int it) {
        int kg = it * 32;
        int k0 = kg + la_k0;
        if (k0 < Dn) {
            float4 v0 = *(const float4*)(xrow + k0);
            float4 v1 = *(const float4*)(xrow + k0 + 4);
            a_pf[0] = (double)v0.x; a_pf[1] = (double)v0.y;
            a_pf[2] = (double)v0.z; a_pf[3] = (double)v0.w;
            a_pf[4] = (double)v1.x; a_pf[5] = (double)v1.y;
            a_pf[6] = (double)v1.z; a_pf[7] = (double)v1.w;
        } else {
            const double* hp = hrow + (k0 - Dn);
            double2 h0v = *(const double2*)(hp + 0);
            double2 h1v = *(const double2*)(hp + 2);
            double2 h2v = *(const double2*)(hp + 4);
            double2 h3v = *(const double2*)(hp + 6);
            a_pf[0] = h0v.x; a_pf[1] = h0v.y; a_pf[2] = h1v.x; a_pf[3] = h1v.y;
            a_pf[4] = h2v.x; a_pf[5] = h2v.y; a_pf[6] = h3v.x; a_pf[7] = h3v.y;
        }
        int kB = kg + lb_k;
        const float* rowp = (kB < Dn) ? (W + (size_t)kB * G4n)
                                      : (U + (size_t)(kB - Dn) * G4n);
        float4 wv = *(const float4*)(rowp + lb_gate * UNITSn + u0 + lb_uoff);
        b_pf[0] = (double)wv.x; b_pf[1] = (double)wv.y;
        b_pf[2] = (double)wv.z; b_pf[3] = (double)wv.w;
    };
    auto store_tiles = [&](int p) {
        double* As = smem + p * 2048;
        double* Bs = smem + 4096 + p * 1024;
        #pragma unroll
        for (int j = 0; j < 8; j++) As[(la_k0 + j) * 64 + la_row] = a_pf[j];
        double2 w0; w0.x = b_pf[0]; w0.y = b_pf[1];
        double2 w1; w1.x = b_pf[2]; w1.y = b_pf[3];
        *(double2*)&Bs[lb_k * 32 + lb_c4] = w0;
        *(double2*)&Bs[lb_k * 32 + lb_c4 + 2] = w1;
    };

    const int lane = tid & 63;
    const int wv_ = tid >> 6;
    const int ri = lane >> 3;
    const int cj = lane & 7;
    const int rb = wv_ * 16 + ri * 2;

    double acc[2][4];
    #pragma unroll
    for (int i = 0; i < 2; i++)
        #pragma unroll
        for (int j = 0; j < 4; j++) acc[i][j] = 0.0;

    prefetch(0);
    store_tiles(0);
    __syncthreads();

    int p = 0;
    for (int it = 0; it < NT; it++) {
        if (it + 1 < NT) prefetch(it + 1);
        {
            const double* As = smem + p * 2048;
            const double* Bs = smem + 4096 + p * 1024;
            #pragma unroll
            for (int k = 0; k < 32; k++) {
                double2 a2 = *(const double2*)&As[k * 64 + rb];
                double2 b0 = *(const double2*)&Bs[k * 32 + cj * 4];
                double2 b1 = *(const double2*)&Bs[k * 32 + cj * 4 + 2];
                acc[0][0] = fma(a2.x, b0.x, acc[0][0]);
                acc[0][1] = fma(a2.x, b0.y, acc[0][1]);
                acc[0][2] = fma(a2.x, b1.x, acc[0][2]);
                acc[0][3] = fma(a2.x, b1.y, acc[0][3]);
                acc[1][0] = fma(a2.y, b0.x, acc[1][0]);
                acc[1][1] = fma(a2.y, b0.y, acc[1][1]);
                acc[1][2] = fma(a2.y, b1.x, acc[1][2]);
                acc[1][3] = fma(a2.y, b1.y, acc[1][3]);
            }
        }
        if (it + 1 < NT) store_tiles(p ^ 1);
        __syncthreads();
        p ^= 1;
    }

    double* zex = smem;
    #pragma unroll
    for (int i = 0; i < 2; i++) {
        double2 z0; z0.x = acc[i][0]; z0.y = acc[i][1];
        double2 z1; z1.x = acc[i][2]; z1.y = acc[i][3];
        *(double2*)&zex[(rb + i) * 32 + cj * 4] = z0;
        *(double2*)&zex[(rb + i) * 32 + cj * 4 + 2] = z1;
    }
    __syncthreads();

    const int eu = tid & 7;
    const int rr = tid >> 3;
    const int ug = u0 + eu;
    const double bi0 = (double)bias[ug];
    const double bf0 = (double)bias[UNITSn + ug];
    const double bc0 = (double)bias[2 * UNITSn + ug];
    const double bo0 = (double)bias[3 * UNITSn + ug];

    #pragma unroll
    for (int s = 0; s < 2; s++) {
        int r = rr + 32 * s;
        int row = rowbase + r;
        double zi = zex[r * 32 + eu]      + bi0;
        double zf = zex[r * 32 + 8 + eu]  + bf0;
        double zc = zex[r * 32 + 16 + eu] + bc0;
        double zo = zex[r * 32 + 24 + eu] + bo0;
        if (t > 0) {
            u64 sp = slots_prev[row];
            int idx = 1023 - (int)(sp & 1023ull);
            const float* wrow = W + (size_t)(Dn + idx) * G4n + ug;
            zi += (double)wrow[0];
            zf += (double)wrow[UNITSn];
            zc += (double)wrow[2 * UNITSn];
            zo += (double)wrow[3 * UNITSn];
            if (ut == 0 && eu == 0) out[(size_t)row * Tn + (t - 1)] = idx;
        }
        size_t off = (size_t)row * UNITSn + ug;
        double cold = cst[off];
        double ig = hsigd(zi), fg = hsigd(zf), og = hsigd(zo);
        double cn = fg * cold + ig * tanh(zc);
        double hn = og * tanh(cn);
        cst[off] = cn;
        hout[off] = hn;
    }
}

// ---------------- Kernel C: logits = h@Wout + bout (fp64), fused argmax ----
#define C_RT 8
#define C_CT 64
#define C_KC 32

__global__ __launch_bounds__(256) void logits_argmax(
    const double* __restrict__ h, const float* __restrict__ Wout,
    const float* __restrict__ bout, u64* __restrict__ slots)
{
    __shared__ double Hs[C_KC][9];
    __shared__ float  Ws[C_KC][C_CT];

    const int tid = threadIdx.x;
    const int ty = tid >> 5;
    const int tx = tid & 31;
    const int rbase = blockIdx.y * C_RT;
    const int cbase = blockIdx.x * C_CT;

    double acc0 = 0.0, acc1 = 0.0;

    const int lh_row = tid >> 5;
    const int lh_kk = tid & 31;
    const int lw_kk = tid >> 4;
    const int lw_j0 = (tid & 15) * 4;

    for (int kb = 0; kb < UNITSn; kb += C_KC) {
        Hs[lh_kk][lh_row] = h[(size_t)(rbase + lh_row) * UNITSn + kb + lh_kk];
        #pragma unroll
        for (int it = 0; it < 2; it++) {
            int kk = lw_kk + it * 16;
            float4 v = *(const float4*)(Wout + (size_t)(kb + kk) * NCn + cbase + lw_j0);
            *(float4*)&Ws[kk][lw_j0] = v;
        }
        __syncthreads();
        #pragma unroll
        for (int kk = 0; kk < C_KC; kk++) {
            double a = Hs[kk][ty];
            float2 wv = *(const float2*)&Ws[kk][tx * 2];
            acc0 = fma(a, (double)wv.x, acc0);
            acc1 = fma(a, (double)wv.y, acc1);
        }
        __syncthreads();
    }

    int col0 = cbase + tx * 2;
    double lg0 = acc0 + (double)bout[col0];
    double lg1 = acc1 + (double)bout[col0 + 1];

    u64 p0 = packlc(lg0, col0);
    u64 p1 = packlc(lg1, col0 + 1);
    u64 best = (p0 > p1) ? p0 : p1;
    #pragma unroll
    for (int off = 16; off >= 1; off >>= 1) {
        u64 o = __shfl_down(best, off, 32);
        if (o > best) best = o;
    }
    if (tx == 0) atomicMax(&slots[rbase + ty], best);
}

// ---------------- final step decode ----------------
__global__ void final_decode(const u64* __restrict__ slots, int* __restrict__ out) {
    int b = threadIdx.x;
    u64 s = slots[b];
    out[(size_t)b * Tn + (Tn - 1)] = 1023 - (int)(s & 1023ull);
}

extern "C" void kernel_launch(void* const* d_in, const int* in_sizes, int n_in,
                              void* d_out, int out_size, void* d_ws, size_t ws_size,
                              hipStream_t stream) {
    const float* x    = (const float*)d_in[0];
    const float* W    = (const float*)d_in[1];
    const float* U    = (const float*)d_in[2];
    const float* bias = (const float*)d_in[3];
    const float* Wout = (const float*)d_in[4];
    const float* bout = (const float*)d_in[5];
    int* out = (int*)d_out;
    char* ws = (char*)d_ws;

    // ws layout: h0 (2MB) | h1 (2MB) | c (2MB) | slots0/1 (4KB) | Wd 48MB @8MB
    double* h0 = (double*)(ws);
    double* h1 = (double*)(ws + (2u << 20));
    double* c  = (double*)(ws + (4u << 20));
    u64* slots0 = (u64*)(ws + (6u << 20));
    u64* slots1 = (u64*)(ws + (6u << 20) + 2048);
    double* Wd  = (double*)(ws + (8u << 20));

    const size_t NEED = (8ull << 20) + (size_t)KTn * G4n * 8;
    const bool big = ws_size >= NEED;

    hipMemsetAsync(d_ws, 0, (6u << 20) + 4096, stream);
    if (big) convert_weights<<<1024, 256, 0, stream>>>(W, U, Wd);

    for (int t = 0; t < Tn; t++) {
        double* hin  = (t & 1) ? h1 : h0;
        double* hout = (t & 1) ? h0 : h1;
        u64* sprev = (t & 1) ? slots0 : slots1;   // written by C(t-1)
        u64* scur  = (t & 1) ? slots1 : slots0;   // zeroed by A(t), written by C(t)
        if (big) {
            lstm_step_mfma<<<dim3(512), 256, 0, stream>>>(x, Wd, W, bias, hin, hout, c,
                                                          sprev, scur, out, t);
        } else {
            lstm_step<<<dim3(512), 256, 0, stream>>>(x, W, U, bias, hin, hout, c,
                                                     sprev, scur, out, t);
        }
        logits_argmax<<<dim3(8, 32), 256, 0, stream>>>(hout, Wout, bout, scur);
    }
    // t = T-1 = 255 (odd) -> its slots live in slots1
    final_decode<<<1, Bn, 0, stream>>>(slots1, out);
}